// Round 3
// baseline (3908.022 us; speedup 1.0000x reference)
//
#include <hip/hip_runtime.h>
#include <math.h>

// ---------------------------------------------------------------------------
// Problem constants
// ---------------------------------------------------------------------------
static constexpr int kH  = 80;
static constexpr int kW  = 120;
static constexpr int kHW = kH * kW;     // 9600
static constexpr int kBV = 6;
static constexpr int kD  = 20;

// ---------------------------------------------------------------------------
// Small helpers
// ---------------------------------------------------------------------------
__device__ __forceinline__ float bf16r(float x) {
  // round-to-nearest-even bf16, returned as float (emulates .astype(bfloat16))
  unsigned u = __float_as_uint(x);
  u += 0x7FFFu + ((u >> 16) & 1u);
  return __uint_as_float(u & 0xFFFF0000u);
}

struct ConstBuf {
  float bn1_s[67], bn1_o[67];
  float bn2_s[64], bn2_o[64];
  float bnf_s[128], bnf_o[128];
  float Kinv[6][9];     // bf16-rounded inv(intrinsics), i-order (b*V+v)
  float Rw[6][9];       // bf16-rounded c2w rotation, i-order
  float tw[6][3];       // bf16-rounded c2w translation, i-order
  float Kinvc[6][9];    // bf16-rounded inv(intr_curr), j-order (v*B+b)
  float intrc[6][9];    // bf16-rounded intr_curr, j-order
  float poseR[2][6][9]; // bf16-rounded pose rotation, [idx-1][j]
  float poseT[2][6][3]; // bf16-rounded pose translation
  float dvals[20];      // bf16-rounded depth values
};

__device__ void inv3x3(const float* A, float* o) {
  float a = A[0], b = A[1], c = A[2];
  float d = A[3], e = A[4], f = A[5];
  float g = A[6], h = A[7], i = A[8];
  float det = a * (e * i - f * h) - b * (d * i - f * g) + c * (d * h - e * g);
  float id = 1.0f / det;
  o[0] = (e * i - f * h) * id;
  o[1] = -(b * i - c * h) * id;
  o[2] = (b * f - c * e) * id;
  o[3] = -(d * i - f * g) * id;
  o[4] = (a * i - c * g) * id;
  o[5] = -(a * f - c * d) * id;
  o[6] = (d * h - e * g) * id;
  o[7] = -(a * h - b * g) * id;
  o[8] = (a * e - b * d) * id;
}

__device__ void inv4x4(const float* A, float* out) {
  // Gauss-Jordan with partial pivoting (mimics LAPACK-style LU inverse)
  float M[4][8];
  for (int r = 0; r < 4; ++r) {
    for (int c = 0; c < 4; ++c) M[r][c] = A[r * 4 + c];
    for (int c = 0; c < 4; ++c) M[r][4 + c] = (r == c) ? 1.0f : 0.0f;
  }
  for (int col = 0; col < 4; ++col) {
    int p = col;
    float best = fabsf(M[col][col]);
    for (int r = col + 1; r < 4; ++r) {
      float v = fabsf(M[r][col]);
      if (v > best) { best = v; p = r; }
    }
    if (p != col) {
      for (int c = 0; c < 8; ++c) {
        float t = M[col][c]; M[col][c] = M[p][c]; M[p][c] = t;
      }
    }
    float inv = 1.0f / M[col][col];
    for (int c = 0; c < 8; ++c) M[col][c] *= inv;
    for (int r = 0; r < 4; ++r) {
      if (r == col) continue;
      float f = M[r][col];
      for (int c = 0; c < 8; ++c) M[r][c] -= f * M[col][c];
    }
  }
  for (int r = 0; r < 4; ++r)
    for (int c = 0; c < 4; ++c) out[r * 4 + c] = M[r][4 + c];
}

__device__ void mm4(const float* A, const float* B, float* C) {
  for (int r = 0; r < 4; ++r)
    for (int c = 0; c < 4; ++c) {
      float s = 0.0f;
      for (int k = 0; k < 4; ++k) s += A[r * 4 + k] * B[k * 4 + c];
      C[r * 4 + c] = s;
    }
}

// ---------------------------------------------------------------------------
// Kernel 0: per-view constants (BN folds, matrix inverses, poses, depth vals)
// ---------------------------------------------------------------------------
__global__ void consts_kernel(const float* __restrict__ intr, const float* __restrict__ c2,
                              const float* g1, const float* b1, const float* m1, const float* v1,
                              const float* g2, const float* b2, const float* m2, const float* v2,
                              const float* gf, const float* bff, const float* mf, const float* vff,
                              ConstBuf* cb) {
  int tid = threadIdx.x;
  for (int c = tid; c < 67; c += 64) {
    float s = g1[c] / sqrtf(v1[c] + 1e-5f);
    cb->bn1_s[c] = s; cb->bn1_o[c] = b1[c] - m1[c] * s;
  }
  for (int c = tid; c < 64; c += 64) {
    float s = g2[c] / sqrtf(v2[c] + 1e-5f);
    cb->bn2_s[c] = s; cb->bn2_o[c] = b2[c] - m2[c] * s;
  }
  for (int c = tid; c < 128; c += 64) {
    float s = gf[c] / sqrtf(vff[c] + 1e-5f);
    cb->bnf_s[c] = s; cb->bnf_o[c] = bff[c] - mf[c] * s;
  }
  if (tid < 20) {
    float l = (1.0f / 19.0f) * (float)tid;           // jnp.linspace step*i
    cb->dvals[tid] = bf16r(1.0f / (0.01f + l * 9.99f));
  }
  __shared__ float Einv_s[6][16];
  if (tid < 6) {
    // i-order (b*V+v) per-view: Kinv, R, t
    float Ki[9];
    inv3x3(intr + tid * 9, Ki);
    for (int k = 0; k < 9; ++k) cb->Kinv[tid][k] = bf16r(Ki[k]);
    const float* T = c2 + tid * 16;
    cb->Rw[tid][0] = bf16r(T[0]);  cb->Rw[tid][1] = bf16r(T[1]);  cb->Rw[tid][2] = bf16r(T[2]);
    cb->Rw[tid][3] = bf16r(T[4]);  cb->Rw[tid][4] = bf16r(T[5]);  cb->Rw[tid][5] = bf16r(T[6]);
    cb->Rw[tid][6] = bf16r(T[8]);  cb->Rw[tid][7] = bf16r(T[9]);  cb->Rw[tid][8] = bf16r(T[10]);
    cb->tw[tid][0] = bf16r(T[3]);  cb->tw[tid][1] = bf16r(T[7]);  cb->tw[tid][2] = bf16r(T[11]);
    inv4x4(T, Einv_s[tid]);
    // j-order (v*B+b): intr_curr (rows scaled by W,H,1) and its inverse
    int vj = tid >> 1, bj = tid & 1, ii = bj * 3 + vj;
    const float* Kk = intr + ii * 9;
    float S[9] = {Kk[0] * 120.0f, Kk[1] * 120.0f, Kk[2] * 120.0f,
                  Kk[3] * 80.0f,  Kk[4] * 80.0f,  Kk[5] * 80.0f,
                  Kk[6],          Kk[7],          Kk[8]};
    for (int k = 0; k < 9; ++k) cb->intrc[tid][k] = bf16r(S[k]);
    float Si[9];
    inv3x3(S, Si);
    for (int k = 0; k < 9; ++k) cb->Kinvc[tid][k] = bf16r(Si[k]);
  }
  __syncthreads();
  if (tid < 12) {
    // pose[idx-1][j] = E[b, (v+idx)%V] @ inv(E[b, v]),  j = v*B + b
    int t = tid / 6, jj = tid % 6;
    int vj = jj >> 1, bj = jj & 1;
    int o = (vj + t + 1) % 3;
    float P[16];
    mm4(c2 + (bj * 3 + o) * 16, Einv_s[bj * 3 + vj], P);
    for (int r = 0; r < 3; ++r) {
      for (int c = 0; c < 3; ++c) cb->poseR[t][jj][r * 3 + c] = bf16r(P[r * 4 + c]);
      cb->poseT[t][jj][r] = bf16r(P[r * 4 + 3]);
    }
  }
}

// ---------------------------------------------------------------------------
// Kernel 1: depth -> world xyz (bf16 chain) -> BN1 -> hn channels 0..2
// ---------------------------------------------------------------------------
__global__ __launch_bounds__(256)
void geom_kernel(const float* __restrict__ x, const ConstBuf* __restrict__ cb,
                 float* __restrict__ hn) {
  int id = blockIdx.x * 256 + threadIdx.x;
  if (id >= kBV * kHW) return;
  int bv = id / kHW, pix = id - bv * kHW;
  int yy = pix / kW, xx = pix - yy * kW;
  float t0 = tanhf(x[(size_t)bv * 64 * kHW + pix]);     // x[:,0]
  float depth = 255.0f * (0.5f * t0 + 0.5f);
  float dz = bf16r(depth);
  float cx = bf16r((float)xx * dz);
  float cy = bf16r((float)yy * dz);
  const float* Ki = cb->Kinv[bv];
  float p0 = bf16r(Ki[0] * cx + Ki[1] * cy + Ki[2] * dz);
  float p1 = bf16r(Ki[3] * cx + Ki[4] * cy + Ki[5] * dz);
  float p2 = bf16r(Ki[6] * cx + Ki[7] * cy + Ki[8] * dz);
  const float* R = cb->Rw[bv];
  const float* tw = cb->tw[bv];
  float q0 = bf16r(bf16r(R[0] * p0 + R[1] * p1 + R[2] * p2) + tw[0]);
  float q1 = bf16r(bf16r(R[3] * p0 + R[4] * p1 + R[5] * p2) + tw[1]);
  float q2 = bf16r(bf16r(R[6] * p0 + R[7] * p1 + R[8] * p2) + tw[2]);
  size_t ob = (size_t)bv * 67 * kHW + pix;
  hn[ob]            = q0 * cb->bn1_s[0] + cb->bn1_o[0];
  hn[ob + kHW]      = q1 * cb->bn1_s[1] + cb->bn1_o[1];
  hn[ob + 2 * kHW]  = q2 * cb->bn1_s[2] + cb->bn1_o[2];
}

// ---------------------------------------------------------------------------
// Kernel 2: x channels -> BN1 -> hn channels 3..66   (float4 elementwise)
// ---------------------------------------------------------------------------
__global__ __launch_bounds__(256)
void pack_x_kernel(const float* __restrict__ x, const ConstBuf* __restrict__ cb,
                   float* __restrict__ hn) {
  int i4 = blockIdx.x * 256 + threadIdx.x;            // over 6*64*9600/4
  int e = i4 * 4;
  int bv = e / (64 * kHW);
  int rem = e - bv * 64 * kHW;
  int c = rem / kHW, p = rem - c * kHW;
  float4 v = *(const float4*)&x[e];
  float s = cb->bn1_s[3 + c], o = cb->bn1_o[3 + c];
  float4 r;
  r.x = v.x * s + o; r.y = v.y * s + o; r.z = v.z * s + o; r.w = v.w * s + o;
  *(float4*)&hn[((size_t)bv * 67 + 3 + c) * kHW + p] = r;
}

// ---------------------------------------------------------------------------
// Direct conv: 32x32 spatial tile, 2x2 px and 4 ocs per thread.
// Optional fused SiLU and fused output-BN (bn2, used by conv1 only).
// ---------------------------------------------------------------------------
template <int K, bool DO_SILU, bool DO_OUTBN>
__global__ __launch_bounds__(256)
void conv_kernel(const float* __restrict__ in, int Cin,
                 const float* __restrict__ wgt, const float* __restrict__ bias,
                 float* __restrict__ out, const ConstBuf* __restrict__ cb) {
  constexpr int PAD = K / 2;
  constexpr int TIN = 32 + K - 1;
  __shared__ float s_in[TIN * TIN];
  __shared__ __align__(16) float s_w[K * K][4];
  const int tid = threadIdx.x;
  const int tx = tid & 15, ty = tid >> 4;
  const int bx = blockIdx.x, by = blockIdx.y;
  const int bv = blockIdx.z >> 4;
  const int oc0 = (blockIdx.z & 15) * 4;
  const int x0 = bx * 32 - PAD, y0 = by * 32 - PAD;
  float acc[2][2][4] = {};
  const float* inb = in + (size_t)bv * Cin * kHW;
  for (int ic = 0; ic < Cin; ++ic) {
    const float* ip = inb + ic * kHW;
    for (int i = tid; i < TIN * TIN; i += 256) {
      int r = i / TIN, c = i - r * TIN;
      int gy = y0 + r, gx = x0 + c;
      float vv = 0.0f;
      if ((unsigned)gy < (unsigned)kH && (unsigned)gx < (unsigned)kW)
        vv = ip[gy * kW + gx];
      s_in[i] = vv;
    }
    const float* wp = wgt + ((size_t)oc0 * Cin + ic) * (K * K);
    for (int i = tid; i < K * K * 4; i += 256) {
      int kk = i >> 2, o = i & 3;
      s_w[kk][o] = wp[(size_t)o * Cin * K * K + kk];
    }
    __syncthreads();
#pragma unroll
    for (int ky = 0; ky < K; ++ky) {
      float a0[K + 1], a1[K + 1];
      const int base = (ty * 2 + ky) * TIN + tx * 2;
#pragma unroll
      for (int c = 0; c <= K; ++c) {
        a0[c] = s_in[base + c];
        a1[c] = s_in[base + TIN + c];
      }
#pragma unroll
      for (int kx = 0; kx < K; ++kx) {
        const float4 w4 = *(const float4*)(&s_w[ky * K + kx][0]);
        const float wv[4] = {w4.x, w4.y, w4.z, w4.w};
#pragma unroll
        for (int o = 0; o < 4; ++o) {
          acc[0][0][o] += a0[kx] * wv[o];
          acc[0][1][o] += a0[kx + 1] * wv[o];
          acc[1][0][o] += a1[kx] * wv[o];
          acc[1][1][o] += a1[kx + 1] * wv[o];
        }
      }
    }
    __syncthreads();
  }
  float bs[4], bnS[4], bnO[4];
#pragma unroll
  for (int o = 0; o < 4; ++o) {
    bs[o] = bias[oc0 + o];
    if (DO_OUTBN) { bnS[o] = cb->bn2_s[oc0 + o]; bnO[o] = cb->bn2_o[oc0 + o]; }
  }
#pragma unroll
  for (int dy = 0; dy < 2; ++dy) {
    int oy = by * 32 + ty * 2 + dy;
    if (oy >= kH) continue;
#pragma unroll
    for (int dx = 0; dx < 2; ++dx) {
      int ox = bx * 32 + tx * 2 + dx;
      if (ox >= kW) continue;
#pragma unroll
      for (int o = 0; o < 4; ++o) {
        float vv = acc[dy][dx][o] + bs[o];
        if (DO_SILU) vv = vv / (1.0f + expf(-vv));
        if (DO_OUTBN) vv = vv * bnS[o] + bnO[o];
        out[(((size_t)bv * 64 + oc0 + o) * kH + oy) * kW + ox] = vv;
      }
    }
  }
}

// ---------------------------------------------------------------------------
// NCHW -> NHWC transpose of the C=64 feature map (for coalesced sampling)
// ---------------------------------------------------------------------------
__global__ __launch_bounds__(256)
void transpose_kernel(const float* __restrict__ h, float* __restrict__ h_cl) {
  __shared__ float s[64][65];
  int blk = blockIdx.x;                 // 6 * 150
  int bv = blk / 150, p0 = (blk - bv * 150) * 64;
  int tid = threadIdx.x;
  for (int i = tid; i < 64 * 64; i += 256) {
    int c = i >> 6, p = i & 63;
    s[c][p] = h[((size_t)bv * 64 + c) * kHW + p0 + p];
  }
  __syncthreads();
  for (int i = tid; i < 64 * 64; i += 256) {
    int p = i >> 6, c = i & 63;
    h_cl[((size_t)bv * kHW + p0 + p) * 64 + c] = s[c][p];
  }
}

// ---------------------------------------------------------------------------
// Plane-sweep correlation: one wave per (j, pixel); lane = channel.
// Emulates the reference's bf16 pts chain; bilinear zeros-pad align-corners.
// Writes corr into cin channels 0..19 (j-order).
// ---------------------------------------------------------------------------
__device__ __forceinline__ float samp(const float* __restrict__ sb, float xf, float yf, int lane) {
  bool valid = (xf >= 0.0f) & (xf < 120.0f) & (yf >= 0.0f) & (yf < 80.0f);
  float xc = fminf(fmaxf(xf, 0.0f), 119.0f);
  float yc = fminf(fmaxf(yf, 0.0f), 79.0f);
  int xi = (int)xc, yi = (int)yc;
  float vv = sb[(size_t)(yi * kW + xi) * 64 + lane];
  return valid ? vv : 0.0f;
}

__global__ __launch_bounds__(256)
void corr_kernel(const float* __restrict__ h_cl, const ConstBuf* __restrict__ cb,
                 float* __restrict__ cin) {
  const int tid = threadIdx.x;
  const int lane = tid & 63;
  const int wid = blockIdx.x * 4 + (tid >> 6);   // 0..57599 over (j, pix)
  const int j = wid / kHW;
  const int pix = wid - j * kHW;
  const int yy = pix / kW, xx = pix - yy * kW;
  const int b = j & 1, v = j >> 1;
  const int dst = b * 3 + v;
  const float f01 = h_cl[((size_t)dst * kHW + pix) * 64 + lane];
  const float* Kc = cb->Kinvc[j];
  const float* IC = cb->intrc[j];
  const float uf = (float)xx, vf = (float)yy;
  float acc[kD];
#pragma unroll
  for (int d = 0; d < kD; ++d) acc[d] = 0.0f;
#pragma unroll
  for (int t = 0; t < 2; ++t) {
    const int src = b * 3 + ((v + t + 1) % 3);
    const float* PR = cb->poseR[t][j];
    const float* PT = cb->poseT[t][j];
    float p1_0 = bf16r(Kc[0] * uf + Kc[1] * vf + Kc[2]);
    float p1_1 = bf16r(Kc[3] * uf + Kc[4] * vf + Kc[5]);
    float p1_2 = bf16r(Kc[6] * uf + Kc[7] * vf + Kc[8]);
    float p2_0 = bf16r(PR[0] * p1_0 + PR[1] * p1_1 + PR[2] * p1_2);
    float p2_1 = bf16r(PR[3] * p1_0 + PR[4] * p1_1 + PR[5] * p1_2);
    float p2_2 = bf16r(PR[6] * p1_0 + PR[7] * p1_1 + PR[8] * p1_2);
    const float* sb = h_cl + (size_t)src * kHW * 64;
#pragma unroll
    for (int d = 0; d < kD; ++d) {
      float dv = cb->dvals[d];
      float q0 = bf16r(bf16r(p2_0 * dv) + PT[0]);
      float q1 = bf16r(bf16r(p2_1 * dv) + PT[1]);
      float q2 = bf16r(bf16r(p2_2 * dv) + PT[2]);
      float s0 = bf16r(IC[0] * q0 + IC[1] * q1 + IC[2] * q2);
      float s1 = bf16r(IC[3] * q0 + IC[4] * q1 + IC[5] * q2);
      float s2 = bf16r(IC[6] * q0 + IC[7] * q1 + IC[8] * q2);
      float den = fmaxf(s2, 1e-3f);
      float g0 = 2.0f * s0 / den / 119.0f - 1.0f;
      float g1 = 2.0f * s1 / den / 79.0f - 1.0f;
      float gx = (g0 + 1.0f) * 0.5f * 119.0f;
      float gy = (g1 + 1.0f) * 0.5f * 79.0f;
      float x0f = floorf(gx), y0f = floorf(gy);
      float wx = gx - x0f, wy = gy - y0f;
      float v00 = samp(sb, x0f,        y0f,        lane);
      float v10 = samp(sb, x0f + 1.0f, y0f,        lane);
      float v01 = samp(sb, x0f,        y0f + 1.0f, lane);
      float v11 = samp(sb, x0f + 1.0f, y0f + 1.0f, lane);
      float val = v00 * ((1.0f - wx) * (1.0f - wy)) + v10 * (wx * (1.0f - wy)) +
                  v01 * ((1.0f - wx) * wy) + v11 * (wx * wy);
      acc[d] += val * f01;
    }
  }
#pragma unroll
  for (int d = 0; d < kD; ++d) {
    float r = acc[d];
#pragma unroll
    for (int off = 32; off > 0; off >>= 1) r += __shfl_xor(r, off, 64);
    if (lane == 0) cin[((size_t)j * 84 + d) * kHW + pix] = r * 0.125f * 0.5f;
  }
}

// ---------------------------------------------------------------------------
// cin channels 20..83 = feat01 (j-order copy of h)
// ---------------------------------------------------------------------------
__global__ __launch_bounds__(256)
void pack_cin_kernel(const float* __restrict__ h, float* __restrict__ cin) {
  int i4 = blockIdx.x * 256 + threadIdx.x;            // over 6*64*9600/4
  int e = i4 * 4;
  int j = e / (64 * kHW);
  int rem = e - j * 64 * kHW;
  int c = rem / kHW, p = rem - c * kHW;
  int dst = (j & 1) * 3 + (j >> 1);
  float4 v = *(const float4*)&h[((size_t)dst * 64 + c) * kHW + p];
  *(float4*)&cin[((size_t)j * 84 + 20 + c) * kHW + p] = v;
}

// ---------------------------------------------------------------------------
// fusedn = BN_cf(concat([cost (reordered j->i), h], channel)) in i-order
// ---------------------------------------------------------------------------
__global__ __launch_bounds__(256)
void pack_fusedn_kernel(const float* __restrict__ cost, const float* __restrict__ h,
                        const ConstBuf* __restrict__ cb, float* __restrict__ fusedn) {
  int i4 = blockIdx.x * 256 + threadIdx.x;            // over 6*128*9600/4
  int e = i4 * 4;
  int i = e / (128 * kHW);
  int rem = e - i * 128 * kHW;
  int ch = rem / kHW, p = rem - ch * kHW;
  int bb = i / 3, vv = i - bb * 3;
  float4 src;
  if (ch < 64) {
    int j = vv * 2 + bb;
    src = *(const float4*)&cost[((size_t)j * 64 + ch) * kHW + p];
  } else {
    src = *(const float4*)&h[((size_t)i * 64 + (ch - 64)) * kHW + p];
  }
  float s = cb->bnf_s[ch], o = cb->bnf_o[ch];
  float4 r;
  r.x = src.x * s + o; r.y = src.y * s + o; r.z = src.z * s + o; r.w = src.w * s + o;
  *(float4*)&fusedn[((size_t)i * 128 + ch) * kHW + p] = r;
}

// ---------------------------------------------------------------------------
// Launch
// ---------------------------------------------------------------------------
extern "C" void kernel_launch(void* const* d_in, const int* in_sizes, int n_in,
                              void* d_out, int out_size, void* d_ws, size_t ws_size,
                              hipStream_t stream) {
  (void)in_sizes; (void)n_in; (void)out_size; (void)ws_size;
  const float* x    = (const float*)d_in[0];
  const float* intr = (const float*)d_in[1];
  const float* c2w  = (const float*)d_in[2];
  const float* bn1g = (const float*)d_in[3];
  const float* bn1b = (const float*)d_in[4];
  const float* bn1m = (const float*)d_in[5];
  const float* bn1v = (const float*)d_in[6];
  const float* w1   = (const float*)d_in[7];
  const float* b1   = (const float*)d_in[8];
  const float* bn2g = (const float*)d_in[9];
  const float* bn2b = (const float*)d_in[10];
  const float* bn2m = (const float*)d_in[11];
  const float* bn2v = (const float*)d_in[12];
  const float* w2   = (const float*)d_in[13];
  const float* b2   = (const float*)d_in[14];
  const float* cpw  = (const float*)d_in[15];
  const float* cpb  = (const float*)d_in[16];
  const float* bnfg = (const float*)d_in[17];
  const float* bnfb = (const float*)d_in[18];
  const float* bnfm = (const float*)d_in[19];
  const float* bnfv = (const float*)d_in[20];
  const float* wf   = (const float*)d_in[21];
  const float* bff  = (const float*)d_in[22];

  ConstBuf* cb = (ConstBuf*)d_ws;
  float* wsf = (float*)((char*)d_ws + 8192);
  // layout (floats from wsf):
  //   hn     @ 0          (6*67*9600  = 3,859,200)
  //   h1     @ 3,859,200  (6*64*9600  = 3,686,400)
  //   h      @ 7,545,600  (3,686,400) persistent
  //   h_cl   @ 0          (reuse hn after conv1)
  //   cin    @ 11,232,000 (6*84*9600  = 4,838,400)
  //   cost   @ 0          (reuse h_cl after corr)
  //   fusedn @ 11,232,000 (reuse cin; 7,372,800) -> total 18,604,800 floats (~75 MB)
  float* hn     = wsf;
  float* h1     = wsf + 3859200;
  float* h      = wsf + 7545600;
  float* h_cl   = wsf;
  float* cin    = wsf + 11232000;
  float* cost   = wsf;
  float* fusedn = wsf + 11232000;

  consts_kernel<<<1, 64, 0, stream>>>(intr, c2w, bn1g, bn1b, bn1m, bn1v,
                                      bn2g, bn2b, bn2m, bn2v, bnfg, bnfb, bnfm, bnfv, cb);
  geom_kernel<<<225, 256, 0, stream>>>(x, cb, hn);
  pack_x_kernel<<<3600, 256, 0, stream>>>(x, cb, hn);
  conv_kernel<9, true, true><<<dim3(4, 3, 96), 256, 0, stream>>>(hn, 67, w1, b1, h1, cb);
  conv_kernel<9, true, false><<<dim3(4, 3, 96), 256, 0, stream>>>(h1, 64, w2, b2, h, cb);
  transpose_kernel<<<900, 256, 0, stream>>>(h, h_cl);
  corr_kernel<<<14400, 256, 0, stream>>>(h_cl, cb, cin);
  pack_cin_kernel<<<3600, 256, 0, stream>>>(h, cin);
  conv_kernel<3, false, false><<<dim3(4, 3, 96), 256, 0, stream>>>(cin, 84, cpw, cpb, cost, cb);
  pack_fusedn_kernel<<<7200, 256, 0, stream>>>(cost, h, cb, fusedn);
  conv_kernel<9, true, false><<<dim3(4, 3, 96), 256, 0, stream>>>(fusedn, 128, wf, bff,
                                                                  (float*)d_out, cb);
}

// Round 5
// 925.843 us; speedup vs baseline: 4.2210x; 4.2210x over previous
//
#include <hip/hip_runtime.h>
#include <math.h>

static constexpr int kH  = 80;
static constexpr int kW  = 120;
static constexpr int kHW = kH * kW;     // 9600
static constexpr int kBV = 6;
static constexpr int kD  = 20;

typedef __attribute__((ext_vector_type(8))) short bf16x8;
typedef __attribute__((ext_vector_type(4))) float f32x4;
typedef __attribute__((ext_vector_type(4))) int   i32x4;
typedef __attribute__((ext_vector_type(2))) int   i32x2;
typedef __attribute__((ext_vector_type(4))) float float4v;

__device__ __forceinline__ float bf16r(float x) {
  unsigned u = __float_as_uint(x);
  u += 0x7FFFu + ((u >> 16) & 1u);
  return __uint_as_float(u & 0xFFFF0000u);
}
__device__ __forceinline__ unsigned short bf16c(float x) {
  unsigned u = __float_as_uint(x);
  u += 0x7FFFu + ((u >> 16) & 1u);
  return (unsigned short)(u >> 16);
}
__device__ __forceinline__ int pack2(float a, float b) {
  return (int)((unsigned)bf16c(a) | ((unsigned)bf16c(b) << 16));
}

struct ConstBuf {
  float bn1_s[67], bn1_o[67];
  float bn2_s[64], bn2_o[64];
  float bnf_s[128], bnf_o[128];
  float Kinv[6][9];
  float Rw[6][9];
  float tw[6][3];
  float Kinvc[6][9];
  float intrc[6][9];
  float poseR[2][6][9];
  float poseT[2][6][3];
  float dvals[20];
};

__device__ void inv3x3(const float* A, float* o) {
  float a = A[0], b = A[1], c = A[2];
  float d = A[3], e = A[4], f = A[5];
  float g = A[6], h = A[7], i = A[8];
  float det = a * (e * i - f * h) - b * (d * i - f * g) + c * (d * h - e * g);
  float id = 1.0f / det;
  o[0] = (e * i - f * h) * id;
  o[1] = -(b * i - c * h) * id;
  o[2] = (b * f - c * e) * id;
  o[3] = -(d * i - f * g) * id;
  o[4] = (a * i - c * g) * id;
  o[5] = -(a * f - c * d) * id;
  o[6] = (d * h - e * g) * id;
  o[7] = -(a * h - b * g) * id;
  o[8] = (a * e - b * d) * id;
}

__device__ void inv4x4(const float* A, float* out) {
  float M[4][8];
  for (int r = 0; r < 4; ++r) {
    for (int c = 0; c < 4; ++c) M[r][c] = A[r * 4 + c];
    for (int c = 0; c < 4; ++c) M[r][4 + c] = (r == c) ? 1.0f : 0.0f;
  }
  for (int col = 0; col < 4; ++col) {
    int p = col;
    float best = fabsf(M[col][col]);
    for (int r = col + 1; r < 4; ++r) {
      float v = fabsf(M[r][col]);
      if (v > best) { best = v; p = r; }
    }
    if (p != col)
      for (int c = 0; c < 8; ++c) { float t = M[col][c]; M[col][c] = M[p][c]; M[p][c] = t; }
    float inv = 1.0f / M[col][col];
    for (int c = 0; c < 8; ++c) M[col][c] *= inv;
    for (int r = 0; r < 4; ++r) {
      if (r == col) continue;
      float f = M[r][col];
      for (int c = 0; c < 8; ++c) M[r][c] -= f * M[col][c];
    }
  }
  for (int r = 0; r < 4; ++r)
    for (int c = 0; c < 4; ++c) out[r * 4 + c] = M[r][4 + c];
}

__device__ void mm4(const float* A, const float* B, float* C) {
  for (int r = 0; r < 4; ++r)
    for (int c = 0; c < 4; ++c) {
      float s = 0.0f;
      for (int k = 0; k < 4; ++k) s += A[r * 4 + k] * B[k * 4 + c];
      C[r * 4 + c] = s;
    }
}

// ---------------------------------------------------------------------------
// Kernel 0: constants
// ---------------------------------------------------------------------------
__global__ void consts_kernel(const float* __restrict__ intr, const float* __restrict__ c2,
                              const float* g1, const float* b1, const float* m1, const float* v1,
                              const float* g2, const float* b2, const float* m2, const float* v2,
                              const float* gf, const float* bff, const float* mf, const float* vff,
                              ConstBuf* cb) {
  int tid = threadIdx.x;
  for (int c = tid; c < 67; c += 64) {
    float s = g1[c] / sqrtf(v1[c] + 1e-5f);
    cb->bn1_s[c] = s; cb->bn1_o[c] = b1[c] - m1[c] * s;
  }
  for (int c = tid; c < 64; c += 64) {
    float s = g2[c] / sqrtf(v2[c] + 1e-5f);
    cb->bn2_s[c] = s; cb->bn2_o[c] = b2[c] - m2[c] * s;
  }
  for (int c = tid; c < 128; c += 64) {
    float s = gf[c] / sqrtf(vff[c] + 1e-5f);
    cb->bnf_s[c] = s; cb->bnf_o[c] = bff[c] - mf[c] * s;
  }
  if (tid < 20) {
    float l = (1.0f / 19.0f) * (float)tid;
    cb->dvals[tid] = bf16r(1.0f / (0.01f + l * 9.99f));
  }
  __shared__ float Einv_s[6][16];
  if (tid < 6) {
    float Ki[9];
    inv3x3(intr + tid * 9, Ki);
    for (int k = 0; k < 9; ++k) cb->Kinv[tid][k] = bf16r(Ki[k]);
    const float* T = c2 + tid * 16;
    cb->Rw[tid][0] = bf16r(T[0]);  cb->Rw[tid][1] = bf16r(T[1]);  cb->Rw[tid][2] = bf16r(T[2]);
    cb->Rw[tid][3] = bf16r(T[4]);  cb->Rw[tid][4] = bf16r(T[5]);  cb->Rw[tid][5] = bf16r(T[6]);
    cb->Rw[tid][6] = bf16r(T[8]);  cb->Rw[tid][7] = bf16r(T[9]);  cb->Rw[tid][8] = bf16r(T[10]);
    cb->tw[tid][0] = bf16r(T[3]);  cb->tw[tid][1] = bf16r(T[7]);  cb->tw[tid][2] = bf16r(T[11]);
    inv4x4(T, Einv_s[tid]);
    int vj = tid >> 1, bj = tid & 1, ii = bj * 3 + vj;
    const float* Kk = intr + ii * 9;
    float S[9] = {Kk[0] * 120.0f, Kk[1] * 120.0f, Kk[2] * 120.0f,
                  Kk[3] * 80.0f,  Kk[4] * 80.0f,  Kk[5] * 80.0f,
                  Kk[6],          Kk[7],          Kk[8]};
    for (int k = 0; k < 9; ++k) cb->intrc[tid][k] = bf16r(S[k]);
    float Si[9];
    inv3x3(S, Si);
    for (int k = 0; k < 9; ++k) cb->Kinvc[tid][k] = bf16r(Si[k]);
  }
  __syncthreads();
  if (tid < 12) {
    int t = tid / 6, jj = tid % 6;
    int vj = jj >> 1, bj = jj & 1;
    int o = (vj + t + 1) % 3;
    float P[16];
    mm4(c2 + (bj * 3 + o) * 16, Einv_s[bj * 3 + vj], P);
    for (int r = 0; r < 3; ++r) {
      for (int c = 0; c < 3; ++c) cb->poseR[t][jj][r * 3 + c] = bf16r(P[r * 4 + c]);
      cb->poseT[t][jj][r] = bf16r(P[r * 4 + 3]);
    }
  }
}

// ---------------------------------------------------------------------------
// Weight prep: OIHW f32 -> lane-ordered bf16 fragments
// Wp unit u = ((kk*NCC + cc)*4 + nt)*64 + lane, 8 ch per unit.
// ---------------------------------------------------------------------------
template <int K, int CINP, int CINR>
__global__ __launch_bounds__(256)
void prep_w(const float* __restrict__ w, unsigned short* __restrict__ Wp) {
  constexpr int NCC = CINP / 32;
  constexpr int NU = K * K * NCC * 4 * 64;
  int u = blockIdx.x * 256 + threadIdx.x;
  if (u >= NU) return;
  int l = u & 63;
  int rest = u >> 6;
  int nt = rest & 3;
  rest >>= 2;
  int cc = rest % NCC;
  int kk = rest / NCC;
  int ky = kk / K, kx = kk - ky * K;
  int oc = nt * 16 + (l & 15);
  int chb = cc * 32 + (l >> 4) * 8;
  unsigned short o[8];
#pragma unroll
  for (int e = 0; e < 8; ++e) {
    int ch = chb + e;
    float val = (ch < CINR) ? w[(((size_t)oc * CINR + ch) * K + ky) * K + kx] : 0.0f;
    o[e] = bf16c(val);
  }
  i32x4 pk;
  pk.x = (int)o[0] | ((int)o[1] << 16);
  pk.y = (int)o[2] | ((int)o[3] << 16);
  pk.z = (int)o[4] | ((int)o[5] << 16);
  pk.w = (int)o[6] | ((int)o[7] << 16);
  *(i32x4*)&Wp[(size_t)u * 8] = pk;
}

// ---------------------------------------------------------------------------
// hn pack: x (NCHW f32) + geometry -> hn_b [bv*9600+pix][96] bf16 (BN1'd)
// ---------------------------------------------------------------------------
__global__ __launch_bounds__(256)
void hn_pack(const float* __restrict__ x, const ConstBuf* __restrict__ cb,
             unsigned short* __restrict__ hn_b) {
  int id = blockIdx.x * 256 + threadIdx.x;
  if (id >= kBV * kHW) return;
  int bv = id / kHW, pix = id - bv * kHW;
  int yy = pix / kW, xx = pix - yy * kW;
  float t0 = tanhf(x[(size_t)bv * 64 * kHW + pix]);
  float depth = 255.0f * (0.5f * t0 + 0.5f);
  float dz = bf16r(depth);
  float cx = bf16r((float)xx * dz);
  float cy = bf16r((float)yy * dz);
  const float* Ki = cb->Kinv[bv];
  float p0 = bf16r(Ki[0] * cx + Ki[1] * cy + Ki[2] * dz);
  float p1 = bf16r(Ki[3] * cx + Ki[4] * cy + Ki[5] * dz);
  float p2 = bf16r(Ki[6] * cx + Ki[7] * cy + Ki[8] * dz);
  const float* R = cb->Rw[bv];
  const float* tw = cb->tw[bv];
  float q[3];
  q[0] = bf16r(bf16r(R[0] * p0 + R[1] * p1 + R[2] * p2) + tw[0]);
  q[1] = bf16r(bf16r(R[3] * p0 + R[4] * p1 + R[5] * p2) + tw[1]);
  q[2] = bf16r(bf16r(R[6] * p0 + R[7] * p1 + R[8] * p2) + tw[2]);
  unsigned short* o = &hn_b[(size_t)id * 96];
  const float* xb = x + (size_t)bv * 64 * kHW + pix;
#pragma unroll
  for (int g = 0; g < 24; ++g) {
    float vv[4];
#pragma unroll
    for (int e = 0; e < 4; ++e) {
      int ch = g * 4 + e;
      float val;
      if (ch < 3) val = q[ch] * cb->bn1_s[ch] + cb->bn1_o[ch];
      else if (ch < 67) val = xb[(size_t)(ch - 3) * kHW] * cb->bn1_s[ch] + cb->bn1_o[ch];
      else val = 0.0f;
      vv[e] = val;
    }
    i32x2 pk = {pack2(vv[0], vv[1]), pack2(vv[2], vv[3])};
    *(i32x2*)(o + g * 4) = pk;
  }
}

// ---------------------------------------------------------------------------
// MFMA implicit-GEMM conv. Tile: 16x8 px, 8 waves, wave = 1 m-tile x 4 n-tiles.
// OUT: 0 = bf16 NHWC, SiLU+BN2 (conv1)
//      1 = f32  NHWC, SiLU      (conv2)
//      2 = bf16 into fusedn[...][0..63], BNf, j->i px remap (cost)
//      3 = f32  NCHW, SiLU      (convf -> d_out)
// ---------------------------------------------------------------------------
template <int CINP, int K, int OUT>
__global__ __launch_bounds__(512)
void conv_mfma(const unsigned short* __restrict__ in_b,
               const unsigned short* __restrict__ Wp,
               const float* __restrict__ bias,
               const ConstBuf* __restrict__ cb,
               float* __restrict__ outf,
               unsigned short* __restrict__ outb) {
  constexpr int NCC = CINP / 32;
  constexpr int PITCH = CINP + 8;        // shorts; *2B stays 16B-aligned
  constexpr int NC = 16 + K - 1;
  constexpr int NR = 8 + K - 1;
  constexpr int NPX = NC * NR;
  constexpr int KK = K * K;
  constexpr int NBU = NCC * 256;         // 16B units per kernel-position
  constexpr int UPB = (NBU + 511) / 512;
  __shared__ unsigned short sA[NPX * PITCH];
  __shared__ unsigned short sB[2][NCC * 2048];

  const int tid = threadIdx.x;
  const int bx = blockIdx.x, by = blockIdx.y, bz = blockIdx.z;
  const int x0 = bx * 16 - (K / 2), y0 = by * 8 - (K / 2);

  // stage A (all channels, once)
  {
    const size_t inbase = (size_t)bz * kHW;
    for (int p = tid; p < NPX; p += 512) {
      int r = p / NC, c = p - r * NC;
      int gy = y0 + r, gx = x0 + c;
      bool ok = ((unsigned)gy < (unsigned)kH) && ((unsigned)gx < (unsigned)kW);
      int gyc = ok ? gy : 0, gxc = ok ? gx : 0;
      const unsigned short* src = &in_b[(inbase + gyc * kW + gxc) * CINP];
      unsigned short* dst = &sA[p * PITCH];
#pragma unroll
      for (int g = 0; g < CINP / 8; ++g) {
        i32x4 v = *(const i32x4*)(src + g * 8);
        if (!ok) v = (i32x4){0, 0, 0, 0};
        *(i32x4*)(dst + g * 8) = v;
      }
    }
  }

  const int wid = tid >> 6, lane = tid & 63;
  const int lm = lane & 15, lg = lane >> 4;
  f32x4 acc[4] = {};

  i32x4 rega[UPB], regb[UPB];
#pragma unroll
  for (int u2 = 0; u2 < UPB; ++u2) {
    int u = tid + u2 * 512;
    if (u < NBU) rega[u2] = *(const i32x4*)&Wp[(size_t)u * 8];
  }
  if (KK > 1) {
#pragma unroll
    for (int u2 = 0; u2 < UPB; ++u2) {
      int u = tid + u2 * 512;
      if (u < NBU) regb[u2] = *(const i32x4*)&Wp[((size_t)NBU + u) * 8];
    }
  }
#pragma unroll
  for (int u2 = 0; u2 < UPB; ++u2) {
    int u = tid + u2 * 512;
    if (u < NBU) *(i32x4*)&sB[0][u * 8] = rega[u2];
  }
  __syncthreads();

  for (int kk = 0; kk < KK; ++kk) {
    // cur = (kk&1)? rega : regb holds W_{kk+1}; stage it into the idle sB half.
    if (kk + 1 < KK) {
#pragma unroll
      for (int u2 = 0; u2 < UPB; ++u2) {
        int u = tid + u2 * 512;
        if (u < NBU) *(i32x4*)&sB[(kk + 1) & 1][u * 8] = ((kk & 1) ? rega : regb)[u2];
      }
    }
    // prefetch W_{kk+2} into the OTHER register buffer (just-consumed one).
    if (kk + 2 < KK) {
#pragma unroll
      for (int u2 = 0; u2 < UPB; ++u2) {
        int u = tid + u2 * 512;
        if (u < NBU)
          ((kk & 1) ? regb : rega)[u2] = *(const i32x4*)&Wp[((size_t)(kk + 2) * NBU + u) * 8];
      }
    }
    const int ky = kk / K, kx = kk - ky * K;
    const unsigned short* ap = &sA[((wid + ky) * NC + lm + kx) * PITCH + lg * 8];
    const unsigned short* bp = &sB[kk & 1][lane * 8];
#pragma unroll
    for (int cc = 0; cc < NCC; ++cc) {
      bf16x8 a = *(const bf16x8*)(ap + cc * 32);
#pragma unroll
      for (int nt = 0; nt < 4; ++nt) {
        bf16x8 b = *(const bf16x8*)(bp + (cc * 4 + nt) * 512);
        acc[nt] = __builtin_amdgcn_mfma_f32_16x16x32_bf16(a, b, acc[nt], 0, 0, 0);
      }
    }
    __syncthreads();
  }

  // epilogue
  const int y = by * 8 + wid;
  const int xbase = bx * 16 + lg * 4;
#pragma unroll
  for (int nt = 0; nt < 4; ++nt) {
    const int oc = nt * 16 + lm;
    const float bs = bias[oc];
    float s2 = 0.f, o2 = 0.f;
    if (OUT == 0) { s2 = cb->bn2_s[oc]; o2 = cb->bn2_o[oc]; }
    if (OUT == 2) { s2 = cb->bnf_s[oc]; o2 = cb->bnf_o[oc]; }
#pragma unroll
    for (int r = 0; r < 4; ++r) {
      int x = xbase + r;
      if (x >= kW) continue;
      float v = acc[nt][r] + bs;
      if (OUT != 2) v = v / (1.0f + expf(-v));   // SiLU
      if (OUT == 0) {
        size_t px = (size_t)bz * kHW + y * kW + x;
        outb[px * 64 + oc] = bf16c(v * s2 + o2);
      } else if (OUT == 1) {
        size_t px = (size_t)bz * kHW + y * kW + x;
        outf[px * 64 + oc] = v;
      } else if (OUT == 2) {
        int i = (bz & 1) * 3 + (bz >> 1);
        size_t px = (size_t)i * kHW + y * kW + x;
        outb[px * 128 + oc] = bf16c(v * s2 + o2);
      } else {
        outf[((size_t)bz * 64 + oc) * kHW + y * kW + x] = v;
      }
    }
  }
}

// ---------------------------------------------------------------------------
// Plane-sweep correlation (f32 math, bf16 emulated grid chain), d-outer.
// Writes cin_b channels 0..19 (j-order rows).
// ---------------------------------------------------------------------------
__device__ __forceinline__ float samp(const float* __restrict__ sb, float xf, float yf, int lane) {
  bool valid = (xf >= 0.0f) & (xf < 120.0f) & (yf >= 0.0f) & (yf < 80.0f);
  float xc = fminf(fmaxf(xf, 0.0f), 119.0f);
  float yc = fminf(fmaxf(yf, 0.0f), 79.0f);
  int xi = (int)xc, yi = (int)yc;
  float vv = sb[(size_t)(yi * kW + xi) * 64 + lane];
  return valid ? vv : 0.0f;
}

__global__ __launch_bounds__(256)
void corr_kernel(const float* __restrict__ h, const ConstBuf* __restrict__ cb,
                 unsigned short* __restrict__ cin_b) {
  const int tid = threadIdx.x;
  const int lane = tid & 63;
  const int wid = blockIdx.x * 4 + (tid >> 6);
  const int j = wid / kHW;
  const int pix = wid - j * kHW;
  const int yy = pix / kW, xx = pix - yy * kW;
  const int b = j & 1, v = j >> 1;
  const float f01 = h[((size_t)(b * 3 + v) * kHW + pix) * 64 + lane];
  const float* Kc = cb->Kinvc[j];
  const float* IC = cb->intrc[j];
  const float uf = (float)xx, vf = (float)yy;
  float p1_0 = bf16r(Kc[0] * uf + Kc[1] * vf + Kc[2]);
  float p1_1 = bf16r(Kc[3] * uf + Kc[4] * vf + Kc[5]);
  float p1_2 = bf16r(Kc[6] * uf + Kc[7] * vf + Kc[8]);
  float p20[2], p21[2], p22[2], pt0[2], pt1[2], pt2[2];
  const float* sbp[2];
#pragma unroll
  for (int t = 0; t < 2; ++t) {
    const float* PR = cb->poseR[t][j];
    const float* PT = cb->poseT[t][j];
    p20[t] = bf16r(PR[0] * p1_0 + PR[1] * p1_1 + PR[2] * p1_2);
    p21[t] = bf16r(PR[3] * p1_0 + PR[4] * p1_1 + PR[5] * p1_2);
    p22[t] = bf16r(PR[6] * p1_0 + PR[7] * p1_1 + PR[8] * p1_2);
    pt0[t] = PT[0]; pt1[t] = PT[1]; pt2[t] = PT[2];
    sbp[t] = h + (size_t)(b * 3 + ((v + t + 1) % 3)) * kHW * 64;
  }
  unsigned short* op = &cin_b[(size_t)wid * 96];
#pragma unroll 2
  for (int d = 0; d < kD; ++d) {
    float dv = cb->dvals[d];
    float accv = 0.0f;
#pragma unroll
    for (int t = 0; t < 2; ++t) {
      float q0 = bf16r(bf16r(p20[t] * dv) + pt0[t]);
      float q1 = bf16r(bf16r(p21[t] * dv) + pt1[t]);
      float q2 = bf16r(bf16r(p22[t] * dv) + pt2[t]);
      float s0 = bf16r(IC[0] * q0 + IC[1] * q1 + IC[2] * q2);
      float s1 = bf16r(IC[3] * q0 + IC[4] * q1 + IC[5] * q2);
      float s2 = bf16r(IC[6] * q0 + IC[7] * q1 + IC[8] * q2);
      float den = fmaxf(s2, 1e-3f);
      float g0 = 2.0f * s0 / den / 119.0f - 1.0f;
      float g1 = 2.0f * s1 / den / 79.0f - 1.0f;
      float gx = (g0 + 1.0f) * 0.5f * 119.0f;
      float gy = (g1 + 1.0f) * 0.5f * 79.0f;
      float x0f = floorf(gx), y0f = floorf(gy);
      float wx = gx - x0f, wy = gy - y0f;
      float v00 = samp(sbp[t], x0f,        y0f,        lane);
      float v10 = samp(sbp[t], x0f + 1.0f, y0f,        lane);
      float v01 = samp(sbp[t], x0f,        y0f + 1.0f, lane);
      float v11 = samp(sbp[t], x0f + 1.0f, y0f + 1.0f, lane);
      float val = v00 * ((1.0f - wx) * (1.0f - wy)) + v10 * (wx * (1.0f - wy)) +
                  v01 * ((1.0f - wx) * wy) + v11 * (wx * wy);
      accv += val * f01;
    }
#pragma unroll
    for (int off = 32; off > 0; off >>= 1) accv += __shfl_xor(accv, off, 64);
    if (lane == 0) op[d] = bf16c(accv * 0.0625f);   // /sqrt(64)/(V-1)
  }
}

// ---------------------------------------------------------------------------
// cin_b ch 20..83 = h (j-reordered), 84..95 = 0
// ---------------------------------------------------------------------------
__global__ __launch_bounds__(256)
void pack_cin(const float* __restrict__ h, unsigned short* __restrict__ cin_b) {
  int id = blockIdx.x * 256 + threadIdx.x;
  if (id >= kBV * kHW) return;
  int j = id / kHW, pix = id - j * kHW;
  int src = (j & 1) * 3 + (j >> 1);
  const float* hr = &h[((size_t)src * kHW + pix) * 64];
  unsigned short* o = &cin_b[(size_t)id * 96];
#pragma unroll
  for (int g = 0; g < 16; ++g) {
    float4v vv = *(const float4v*)(hr + g * 4);
    i32x2 pk = {pack2(vv.x, vv.y), pack2(vv.z, vv.w)};
    *(i32x2*)(o + 20 + g * 4) = pk;
  }
  i32x2 z = {0, 0};
  *(i32x2*)(o + 84) = z;
  *(i32x2*)(o + 88) = z;
  *(i32x2*)(o + 92) = z;
}

// ---------------------------------------------------------------------------
// fusedn_b ch 64..127 = BNf(h) (i-order)
// ---------------------------------------------------------------------------
__global__ __launch_bounds__(256)
void pack_fusedn(const float* __restrict__ h, const ConstBuf* __restrict__ cb,
                 unsigned short* __restrict__ fusedn_b) {
  int id = blockIdx.x * 256 + threadIdx.x;
  if (id >= kBV * kHW) return;
  const float* hr = &h[(size_t)id * 64];
  unsigned short* o = &fusedn_b[(size_t)id * 128 + 64];
#pragma unroll
  for (int g = 0; g < 16; ++g) {
    float4v vv = *(const float4v*)(hr + g * 4);
    float r0 = vv.x * cb->bnf_s[64 + g * 4 + 0] + cb->bnf_o[64 + g * 4 + 0];
    float r1 = vv.y * cb->bnf_s[64 + g * 4 + 1] + cb->bnf_o[64 + g * 4 + 1];
    float r2 = vv.z * cb->bnf_s[64 + g * 4 + 2] + cb->bnf_o[64 + g * 4 + 2];
    float r3 = vv.w * cb->bnf_s[64 + g * 4 + 3] + cb->bnf_o[64 + g * 4 + 3];
    i32x2 pk = {pack2(r0, r1), pack2(r2, r3)};
    *(i32x2*)(o + g * 4) = pk;
  }
}

// ---------------------------------------------------------------------------
// Launch
// ---------------------------------------------------------------------------
extern "C" void kernel_launch(void* const* d_in, const int* in_sizes, int n_in,
                              void* d_out, int out_size, void* d_ws, size_t ws_size,
                              hipStream_t stream) {
  (void)in_sizes; (void)n_in; (void)out_size; (void)ws_size;
  const float* x    = (const float*)d_in[0];
  const float* intr = (const float*)d_in[1];
  const float* c2w  = (const float*)d_in[2];
  const float* bn1g = (const float*)d_in[3];
  const float* bn1b = (const float*)d_in[4];
  const float* bn1m = (const float*)d_in[5];
  const float* bn1v = (const float*)d_in[6];
  const float* w1   = (const float*)d_in[7];
  const float* b1   = (const float*)d_in[8];
  const float* bn2g = (const float*)d_in[9];
  const float* bn2b = (const float*)d_in[10];
  const float* bn2m = (const float*)d_in[11];
  const float* bn2v = (const float*)d_in[12];
  const float* w2   = (const float*)d_in[13];
  const float* b2   = (const float*)d_in[14];
  const float* cpw  = (const float*)d_in[15];
  const float* cpb  = (const float*)d_in[16];
  const float* bnfg = (const float*)d_in[17];
  const float* bnfb = (const float*)d_in[18];
  const float* bnfm = (const float*)d_in[19];
  const float* bnfv = (const float*)d_in[20];
  const float* wf   = (const float*)d_in[21];
  const float* bff  = (const float*)d_in[22];

  char* ws = (char*)d_ws;
  ConstBuf* cb            = (ConstBuf*)ws;
  unsigned short* hn_b    = (unsigned short*)(ws + 8192);        // 6*9600*96*2
  unsigned short* h1_b    = (unsigned short*)(ws + 11067392);    // 6*9600*64*2
  float*          h       = (float*)(ws + 18440192);             // 6*9600*64*4
  unsigned short* cin_b   = (unsigned short*)(ws + 33185792);    // 6*9600*96*2
  unsigned short* fused_b = (unsigned short*)(ws + 44244992);    // 6*9600*128*2
  unsigned short* Wp1     = (unsigned short*)(ws + 58990592);    // 995328 B
  unsigned short* Wp2     = (unsigned short*)(ws + 59985920);    // 663552 B
  unsigned short* Wpc     = (unsigned short*)(ws + 60649472);    // 110592 B
  unsigned short* Wpf     = (unsigned short*)(ws + 60760064);    // 1327104 B

  consts_kernel<<<1, 64, 0, stream>>>(intr, c2w, bn1g, bn1b, bn1m, bn1v,
                                      bn2g, bn2b, bn2m, bn2v, bnfg, bnfb, bnfm, bnfv, cb);
  prep_w<9, 96, 67><<<243, 256, 0, stream>>>(w1, Wp1);
  prep_w<9, 64, 64><<<162, 256, 0, stream>>>(w2, Wp2);
  prep_w<3, 96, 84><<<27, 256, 0, stream>>>(cpw, Wpc);
  prep_w<9, 128, 128><<<324, 256, 0, stream>>>(wf, Wpf);
  hn_pack<<<225, 256, 0, stream>>>(x, cb, hn_b);

  dim3 cgrid(8, 10, 6);
  conv_mfma<96, 9, 0><<<cgrid, 512, 0, stream>>>(hn_b, Wp1, b1, cb, nullptr, h1_b);
  conv_mfma<64, 9, 1><<<cgrid, 512, 0, stream>>>(h1_b, Wp2, b2, cb, h, nullptr);
  corr_kernel<<<14400, 256, 0, stream>>>(h, cb, cin_b);
  pack_cin<<<225, 256, 0, stream>>>(h, cin_b);
  conv_mfma<96, 3, 2><<<cgrid, 512, 0, stream>>>(cin_b, Wpc, cpb, cb, nullptr, fused_b);
  pack_fusedn<<<225, 256, 0, stream>>>(h, cb, fused_b);
  conv_mfma<128, 9, 3><<<cgrid, 512, 0, stream>>>(fused_b, Wpf, bff, cb, (float*)d_out, nullptr);
}

// Round 6
// 538.153 us; speedup vs baseline: 7.2619x; 1.7204x over previous
//
#include <hip/hip_runtime.h>
#include <math.h>

static constexpr int kH  = 80;
static constexpr int kW  = 120;
static constexpr int kHW = kH * kW;     // 9600
static constexpr int kBV = 6;
static constexpr int kD  = 20;

typedef __attribute__((ext_vector_type(8))) short bf16x8;
typedef __attribute__((ext_vector_type(4))) float f32x4;
typedef __attribute__((ext_vector_type(4))) int   i32x4;
typedef __attribute__((ext_vector_type(2))) int   i32x2;
typedef __attribute__((ext_vector_type(4))) float float4v;

__device__ __forceinline__ float bf16r(float x) {
  unsigned u = __float_as_uint(x);
  u += 0x7FFFu + ((u >> 16) & 1u);
  return __uint_as_float(u & 0xFFFF0000u);
}
__device__ __forceinline__ unsigned short bf16c(float x) {
  unsigned u = __float_as_uint(x);
  u += 0x7FFFu + ((u >> 16) & 1u);
  return (unsigned short)(u >> 16);
}
__device__ __forceinline__ int pack2(float a, float b) {
  return (int)((unsigned)bf16c(a) | ((unsigned)bf16c(b) << 16));
}

struct ConstBuf {
  float bn1_s[67], bn1_o[67];
  float bn2_s[64], bn2_o[64];
  float bnf_s[128], bnf_o[128];
  float Kinv[6][9];
  float Rw[6][9];
  float tw[6][3];
  float Kinvc[6][9];
  float intrc[6][9];
  float poseR[2][6][9];
  float poseT[2][6][3];
  float dvals[20];
};

__device__ void inv3x3(const float* A, float* o) {
  float a = A[0], b = A[1], c = A[2];
  float d = A[3], e = A[4], f = A[5];
  float g = A[6], h = A[7], i = A[8];
  float det = a * (e * i - f * h) - b * (d * i - f * g) + c * (d * h - e * g);
  float id = 1.0f / det;
  o[0] = (e * i - f * h) * id;
  o[1] = -(b * i - c * h) * id;
  o[2] = (b * f - c * e) * id;
  o[3] = -(d * i - f * g) * id;
  o[4] = (a * i - c * g) * id;
  o[5] = -(a * f - c * d) * id;
  o[6] = (d * h - e * g) * id;
  o[7] = -(a * h - b * g) * id;
  o[8] = (a * e - b * d) * id;
}

__device__ void inv4x4(const float* A, float* out) {
  float M[4][8];
  for (int r = 0; r < 4; ++r) {
    for (int c = 0; c < 4; ++c) M[r][c] = A[r * 4 + c];
    for (int c = 0; c < 4; ++c) M[r][4 + c] = (r == c) ? 1.0f : 0.0f;
  }
  for (int col = 0; col < 4; ++col) {
    int p = col;
    float best = fabsf(M[col][col]);
    for (int r = col + 1; r < 4; ++r) {
      float v = fabsf(M[r][col]);
      if (v > best) { best = v; p = r; }
    }
    if (p != col)
      for (int c = 0; c < 8; ++c) { float t = M[col][c]; M[col][c] = M[p][c]; M[p][c] = t; }
    float inv = 1.0f / M[col][col];
    for (int c = 0; c < 8; ++c) M[col][c] *= inv;
    for (int r = 0; r < 4; ++r) {
      if (r == col) continue;
      float f = M[r][col];
      for (int c = 0; c < 8; ++c) M[r][c] -= f * M[col][c];
    }
  }
  for (int r = 0; r < 4; ++r)
    for (int c = 0; c < 4; ++c) out[r * 4 + c] = M[r][4 + c];
}

__device__ void mm4(const float* A, const float* B, float* C) {
  for (int r = 0; r < 4; ++r)
    for (int c = 0; c < 4; ++c) {
      float s = 0.0f;
      for (int k = 0; k < 4; ++k) s += A[r * 4 + k] * B[k * 4 + c];
      C[r * 4 + c] = s;
    }
}

// ---------------------------------------------------------------------------
// Kernel 0: constants
// ---------------------------------------------------------------------------
__global__ void consts_kernel(const float* __restrict__ intr, const float* __restrict__ c2,
                              const float* g1, const float* b1, const float* m1, const float* v1,
                              const float* g2, const float* b2, const float* m2, const float* v2,
                              const float* gf, const float* bff, const float* mf, const float* vff,
                              ConstBuf* cb) {
  int tid = threadIdx.x;
  for (int c = tid; c < 67; c += 64) {
    float s = g1[c] / sqrtf(v1[c] + 1e-5f);
    cb->bn1_s[c] = s; cb->bn1_o[c] = b1[c] - m1[c] * s;
  }
  for (int c = tid; c < 64; c += 64) {
    float s = g2[c] / sqrtf(v2[c] + 1e-5f);
    cb->bn2_s[c] = s; cb->bn2_o[c] = b2[c] - m2[c] * s;
  }
  for (int c = tid; c < 128; c += 64) {
    float s = gf[c] / sqrtf(vff[c] + 1e-5f);
    cb->bnf_s[c] = s; cb->bnf_o[c] = bff[c] - mf[c] * s;
  }
  if (tid < 20) {
    float l = (1.0f / 19.0f) * (float)tid;
    cb->dvals[tid] = bf16r(1.0f / (0.01f + l * 9.99f));
  }
  __shared__ float Einv_s[6][16];
  if (tid < 6) {
    float Ki[9];
    inv3x3(intr + tid * 9, Ki);
    for (int k = 0; k < 9; ++k) cb->Kinv[tid][k] = bf16r(Ki[k]);
    const float* T = c2 + tid * 16;
    cb->Rw[tid][0] = bf16r(T[0]);  cb->Rw[tid][1] = bf16r(T[1]);  cb->Rw[tid][2] = bf16r(T[2]);
    cb->Rw[tid][3] = bf16r(T[4]);  cb->Rw[tid][4] = bf16r(T[5]);  cb->Rw[tid][5] = bf16r(T[6]);
    cb->Rw[tid][6] = bf16r(T[8]);  cb->Rw[tid][7] = bf16r(T[9]);  cb->Rw[tid][8] = bf16r(T[10]);
    cb->tw[tid][0] = bf16r(T[3]);  cb->tw[tid][1] = bf16r(T[7]);  cb->tw[tid][2] = bf16r(T[11]);
    inv4x4(T, Einv_s[tid]);
    int vj = tid >> 1, bj = tid & 1, ii = bj * 3 + vj;
    const float* Kk = intr + ii * 9;
    float S[9] = {Kk[0] * 120.0f, Kk[1] * 120.0f, Kk[2] * 120.0f,
                  Kk[3] * 80.0f,  Kk[4] * 80.0f,  Kk[5] * 80.0f,
                  Kk[6],          Kk[7],          Kk[8]};
    for (int k = 0; k < 9; ++k) cb->intrc[tid][k] = bf16r(S[k]);
    float Si[9];
    inv3x3(S, Si);
    for (int k = 0; k < 9; ++k) cb->Kinvc[tid][k] = bf16r(Si[k]);
  }
  __syncthreads();
  if (tid < 12) {
    int t = tid / 6, jj = tid % 6;
    int vj = jj >> 1, bj = jj & 1;
    int o = (vj + t + 1) % 3;
    float P[16];
    mm4(c2 + (bj * 3 + o) * 16, Einv_s[bj * 3 + vj], P);
    for (int r = 0; r < 3; ++r) {
      for (int c = 0; c < 3; ++c) cb->poseR[t][jj][r * 3 + c] = bf16r(P[r * 4 + c]);
      cb->poseT[t][jj][r] = bf16r(P[r * 4 + 3]);
    }
  }
}

// ---------------------------------------------------------------------------
// Weight prep: OIHW f32 -> lane-ordered bf16 fragments
// Wp unit u = ((kk*NCC + cc)*4 + nt)*64 + lane, 8 ch per unit.
// ---------------------------------------------------------------------------
template <int K, int CINP, int CINR>
__global__ __launch_bounds__(256)
void prep_w(const float* __restrict__ w, unsigned short* __restrict__ Wp) {
  constexpr int NCC = CINP / 32;
  constexpr int NU = K * K * NCC * 4 * 64;
  int u = blockIdx.x * 256 + threadIdx.x;
  if (u >= NU) return;
  int l = u & 63;
  int rest = u >> 6;
  int nt = rest & 3;
  rest >>= 2;
  int cc = rest % NCC;
  int kk = rest / NCC;
  int ky = kk / K, kx = kk - ky * K;
  int oc = nt * 16 + (l & 15);
  int chb = cc * 32 + (l >> 4) * 8;
  unsigned short o[8];
#pragma unroll
  for (int e = 0; e < 8; ++e) {
    int ch = chb + e;
    float val = (ch < CINR) ? w[(((size_t)oc * CINR + ch) * K + ky) * K + kx] : 0.0f;
    o[e] = bf16c(val);
  }
  i32x4 pk;
  pk.x = (int)o[0] | ((int)o[1] << 16);
  pk.y = (int)o[2] | ((int)o[3] << 16);
  pk.z = (int)o[4] | ((int)o[5] << 16);
  pk.w = (int)o[6] | ((int)o[7] << 16);
  *(i32x4*)&Wp[(size_t)u * 8] = pk;
}

// ---------------------------------------------------------------------------
// hn pack: x (NCHW f32) + geometry -> hn_b [bv*9600+pix][96] bf16 (BN1'd)
// ---------------------------------------------------------------------------
__global__ __launch_bounds__(256)
void hn_pack(const float* __restrict__ x, const ConstBuf* __restrict__ cb,
             unsigned short* __restrict__ hn_b) {
  int id = blockIdx.x * 256 + threadIdx.x;
  if (id >= kBV * kHW) return;
  int bv = id / kHW, pix = id - bv * kHW;
  int yy = pix / kW, xx = pix - yy * kW;
  float t0 = tanhf(x[(size_t)bv * 64 * kHW + pix]);
  float depth = 255.0f * (0.5f * t0 + 0.5f);
  float dz = bf16r(depth);
  float cx = bf16r((float)xx * dz);
  float cy = bf16r((float)yy * dz);
  const float* Ki = cb->Kinv[bv];
  float p0 = bf16r(Ki[0] * cx + Ki[1] * cy + Ki[2] * dz);
  float p1 = bf16r(Ki[3] * cx + Ki[4] * cy + Ki[5] * dz);
  float p2 = bf16r(Ki[6] * cx + Ki[7] * cy + Ki[8] * dz);
  const float* R = cb->Rw[bv];
  const float* tw = cb->tw[bv];
  float q[3];
  q[0] = bf16r(bf16r(R[0] * p0 + R[1] * p1 + R[2] * p2) + tw[0]);
  q[1] = bf16r(bf16r(R[3] * p0 + R[4] * p1 + R[5] * p2) + tw[1]);
  q[2] = bf16r(bf16r(R[6] * p0 + R[7] * p1 + R[8] * p2) + tw[2]);
  unsigned short* o = &hn_b[(size_t)id * 96];
  const float* xb = x + (size_t)bv * 64 * kHW + pix;
#pragma unroll
  for (int g = 0; g < 24; ++g) {
    float vv[4];
#pragma unroll
    for (int e = 0; e < 4; ++e) {
      int ch = g * 4 + e;
      float val;
      if (ch < 3) val = q[ch] * cb->bn1_s[ch] + cb->bn1_o[ch];
      else if (ch < 67) val = xb[(size_t)(ch - 3) * kHW] * cb->bn1_s[ch] + cb->bn1_o[ch];
      else val = 0.0f;
      vv[e] = val;
    }
    i32x2 pk = {pack2(vv[0], vv[1]), pack2(vv[2], vv[3])};
    *(i32x2*)(o + g * 4) = pk;
  }
}

// ---------------------------------------------------------------------------
// MFMA implicit-GEMM conv. Tile: 16x8 px, 8 waves, wave = 1 m-tile x 4 n-tiles.
// OUT: 0 = bf16 NHWC, SiLU+BN2 (conv1)
//      1 = f32  NHWC, SiLU      (conv2)
//      2 = bf16 into fusedn[...][0..63], BNf, j->i px remap (cost)
//      3 = f32  NCHW, SiLU      (convf -> d_out)
// ---------------------------------------------------------------------------
template <int CINP, int K, int OUT>
__global__ __launch_bounds__(512)
void conv_mfma(const unsigned short* __restrict__ in_b,
               const unsigned short* __restrict__ Wp,
               const float* __restrict__ bias,
               const ConstBuf* __restrict__ cb,
               float* __restrict__ outf,
               unsigned short* __restrict__ outb) {
  constexpr int NCC = CINP / 32;
  constexpr int PITCH = CINP + 8;        // shorts; *2B stays 16B-aligned
  constexpr int NC = 16 + K - 1;
  constexpr int NR = 8 + K - 1;
  constexpr int NPX = NC * NR;
  constexpr int KK = K * K;
  constexpr int NBU = NCC * 256;         // 16B units per kernel-position
  constexpr int UPB = (NBU + 511) / 512;
  __shared__ unsigned short sA[NPX * PITCH];
  __shared__ unsigned short sB[2][NCC * 2048];

  const int tid = threadIdx.x;
  const int bx = blockIdx.x, by = blockIdx.y, bz = blockIdx.z;
  const int x0 = bx * 16 - (K / 2), y0 = by * 8 - (K / 2);

  // stage A (all channels, once)
  {
    const size_t inbase = (size_t)bz * kHW;
    for (int p = tid; p < NPX; p += 512) {
      int r = p / NC, c = p - r * NC;
      int gy = y0 + r, gx = x0 + c;
      bool ok = ((unsigned)gy < (unsigned)kH) && ((unsigned)gx < (unsigned)kW);
      int gyc = ok ? gy : 0, gxc = ok ? gx : 0;
      const unsigned short* src = &in_b[(inbase + gyc * kW + gxc) * CINP];
      unsigned short* dst = &sA[p * PITCH];
#pragma unroll
      for (int g = 0; g < CINP / 8; ++g) {
        i32x4 v = *(const i32x4*)(src + g * 8);
        if (!ok) v = (i32x4){0, 0, 0, 0};
        *(i32x4*)(dst + g * 8) = v;
      }
    }
  }

  const int wid = tid >> 6, lane = tid & 63;
  const int lm = lane & 15, lg = lane >> 4;
  f32x4 acc[4] = {};

  i32x4 rega[UPB], regb[UPB];
#pragma unroll
  for (int u2 = 0; u2 < UPB; ++u2) {
    int u = tid + u2 * 512;
    if (u < NBU) rega[u2] = *(const i32x4*)&Wp[(size_t)u * 8];
  }
  if (KK > 1) {
#pragma unroll
    for (int u2 = 0; u2 < UPB; ++u2) {
      int u = tid + u2 * 512;
      if (u < NBU) regb[u2] = *(const i32x4*)&Wp[((size_t)NBU + u) * 8];
    }
  }
#pragma unroll
  for (int u2 = 0; u2 < UPB; ++u2) {
    int u = tid + u2 * 512;
    if (u < NBU) *(i32x4*)&sB[0][u * 8] = rega[u2];
  }
  __syncthreads();

  for (int kk = 0; kk < KK; ++kk) {
    // cur = (kk&1)? rega : regb holds W_{kk+1}; stage it into the idle sB half.
    if (kk + 1 < KK) {
#pragma unroll
      for (int u2 = 0; u2 < UPB; ++u2) {
        int u = tid + u2 * 512;
        if (u < NBU) *(i32x4*)&sB[(kk + 1) & 1][u * 8] = ((kk & 1) ? rega : regb)[u2];
      }
    }
    // prefetch W_{kk+2} into the OTHER register buffer (just-consumed one).
    if (kk + 2 < KK) {
#pragma unroll
      for (int u2 = 0; u2 < UPB; ++u2) {
        int u = tid + u2 * 512;
        if (u < NBU)
          ((kk & 1) ? regb : rega)[u2] = *(const i32x4*)&Wp[((size_t)(kk + 2) * NBU + u) * 8];
      }
    }
    const int ky = kk / K, kx = kk - ky * K;
    const unsigned short* ap = &sA[((wid + ky) * NC + lm + kx) * PITCH + lg * 8];
    const unsigned short* bp = &sB[kk & 1][lane * 8];
#pragma unroll
    for (int cc = 0; cc < NCC; ++cc) {
      bf16x8 a = *(const bf16x8*)(ap + cc * 32);
#pragma unroll
      for (int nt = 0; nt < 4; ++nt) {
        bf16x8 b = *(const bf16x8*)(bp + (cc * 4 + nt) * 512);
        acc[nt] = __builtin_amdgcn_mfma_f32_16x16x32_bf16(a, b, acc[nt], 0, 0, 0);
      }
    }
    __syncthreads();
  }

  // epilogue
  const int y = by * 8 + wid;
  const int xbase = bx * 16 + lg * 4;
#pragma unroll
  for (int nt = 0; nt < 4; ++nt) {
    const int oc = nt * 16 + lm;
    const float bs = bias[oc];
    float s2 = 0.f, o2 = 0.f;
    if (OUT == 0) { s2 = cb->bn2_s[oc]; o2 = cb->bn2_o[oc]; }
    if (OUT == 2) { s2 = cb->bnf_s[oc]; o2 = cb->bnf_o[oc]; }
#pragma unroll
    for (int r = 0; r < 4; ++r) {
      int x = xbase + r;
      if (x >= kW) continue;
      float v = acc[nt][r] + bs;
      if (OUT != 2) v = v / (1.0f + expf(-v));   // SiLU
      if (OUT == 0) {
        size_t px = (size_t)bz * kHW + y * kW + x;
        outb[px * 64 + oc] = bf16c(v * s2 + o2);
      } else if (OUT == 1) {
        size_t px = (size_t)bz * kHW + y * kW + x;
        outf[px * 64 + oc] = v;
      } else if (OUT == 2) {
        int i = (bz & 1) * 3 + (bz >> 1);
        size_t px = (size_t)i * kHW + y * kW + x;
        outb[px * 128 + oc] = bf16c(v * s2 + o2);
      } else {
        outf[((size_t)bz * 64 + oc) * kHW + y * kW + x] = v;
      }
    }
  }
}

// ---------------------------------------------------------------------------
// Plane-sweep correlation, lane-parallel geometry:
// lanes 0..39 compute the bf16-emulated grid chain for (d,t)=(lane>>1,lane&1),
// publish {row0,row1,col0,col1 (float-index offsets), w00,w10,w01,w11} to LDS;
// sampling loop reads them as lane-uniform broadcasts.
// ---------------------------------------------------------------------------
__global__ __launch_bounds__(256)
void corr_kernel(const float* __restrict__ h, const ConstBuf* __restrict__ cb,
                 unsigned short* __restrict__ cin_b) {
  __shared__ float sgeo[4][40][8];
  const int tid = threadIdx.x;
  const int w = tid >> 6, lane = tid & 63;
  const int wid = blockIdx.x * 4 + w;
  const int j = wid / kHW;
  const int pix = wid - j * kHW;
  const int yy = pix / kW, xx = pix - yy * kW;
  const int b = j & 1, v = j >> 1;
  const float f01 = h[((size_t)(b * 3 + v) * kHW + pix) * 64 + lane];
  const float* sbp0 = h + (size_t)(b * 3 + ((v + 1) % 3)) * kHW * 64;
  const float* sbp1 = h + (size_t)(b * 3 + ((v + 2) % 3)) * kHW * 64;

  if (lane < 40) {
    const int d = lane >> 1, t = lane & 1;
    const float* Kc = cb->Kinvc[j];
    const float* IC = cb->intrc[j];
    const float uf = (float)xx, vf = (float)yy;
    float p1_0 = bf16r(Kc[0] * uf + Kc[1] * vf + Kc[2]);
    float p1_1 = bf16r(Kc[3] * uf + Kc[4] * vf + Kc[5]);
    float p1_2 = bf16r(Kc[6] * uf + Kc[7] * vf + Kc[8]);
    const float* PR = cb->poseR[t][j];
    const float* PT = cb->poseT[t][j];
    float p20 = bf16r(PR[0] * p1_0 + PR[1] * p1_1 + PR[2] * p1_2);
    float p21 = bf16r(PR[3] * p1_0 + PR[4] * p1_1 + PR[5] * p1_2);
    float p22 = bf16r(PR[6] * p1_0 + PR[7] * p1_1 + PR[8] * p1_2);
    float dv = cb->dvals[d];
    float q0 = bf16r(bf16r(p20 * dv) + PT[0]);
    float q1 = bf16r(bf16r(p21 * dv) + PT[1]);
    float q2 = bf16r(bf16r(p22 * dv) + PT[2]);
    float s0 = bf16r(IC[0] * q0 + IC[1] * q1 + IC[2] * q2);
    float s1 = bf16r(IC[3] * q0 + IC[4] * q1 + IC[5] * q2);
    float s2 = bf16r(IC[6] * q0 + IC[7] * q1 + IC[8] * q2);
    float den = fmaxf(s2, 1e-3f);
    float g0 = 2.0f * s0 / den / 119.0f - 1.0f;
    float g1 = 2.0f * s1 / den / 79.0f - 1.0f;
    float gx = (g0 + 1.0f) * 0.5f * 119.0f;
    float gy = (g1 + 1.0f) * 0.5f * 79.0f;
    float x0f = floorf(gx), y0f = floorf(gy);
    float wx = gx - x0f, wy = gy - y0f;
    float x1f = x0f + 1.0f, y1f = y0f + 1.0f;
    float vx0 = (x0f >= 0.0f && x0f < 120.0f) ? 1.0f : 0.0f;
    float vx1 = (x1f >= 0.0f && x1f < 120.0f) ? 1.0f : 0.0f;
    float vy0 = (y0f >= 0.0f && y0f < 80.0f) ? 1.0f : 0.0f;
    float vy1 = (y1f >= 0.0f && y1f < 80.0f) ? 1.0f : 0.0f;
    int xi0 = (int)fminf(fmaxf(x0f, 0.0f), 119.0f);
    int xi1 = (int)fminf(fmaxf(x1f, 0.0f), 119.0f);
    int yi0 = (int)fminf(fmaxf(y0f, 0.0f), 79.0f);
    int yi1 = (int)fminf(fmaxf(y1f, 0.0f), 79.0f);
    float* gp = sgeo[w][lane];
    gp[0] = __int_as_float(yi0 * (kW * 64));
    gp[1] = __int_as_float(yi1 * (kW * 64));
    gp[2] = __int_as_float(xi0 * 64);
    gp[3] = __int_as_float(xi1 * 64);
    gp[4] = ((1.0f - wx) * (1.0f - wy)) * (vx0 * vy0);
    gp[5] = (wx * (1.0f - wy)) * (vx1 * vy0);
    gp[6] = ((1.0f - wx) * wy) * (vx0 * vy1);
    gp[7] = (wx * wy) * (vx1 * vy1);
  }
  __syncthreads();

  unsigned short* op = &cin_b[(size_t)wid * 96];
#pragma unroll 2
  for (int d = 0; d < kD; ++d) {
    float a = 0.0f;
#pragma unroll
    for (int t = 0; t < 2; ++t) {
      const float* sb = t ? sbp1 : sbp0;
      const float* gp = sgeo[w][d * 2 + t];
      float4v ga = *(const float4v*)gp;
      float4v gb = *(const float4v*)(gp + 4);
      int r0 = __float_as_int(ga.x), r1 = __float_as_int(ga.y);
      int c0 = __float_as_int(ga.z), c1 = __float_as_int(ga.w);
      float v00 = sb[r0 + c0 + lane];
      float v10 = sb[r0 + c1 + lane];
      float v01 = sb[r1 + c0 + lane];
      float v11 = sb[r1 + c1 + lane];
      a += gb.x * v00 + gb.y * v10 + gb.z * v01 + gb.w * v11;
    }
    float r = a * f01;
#pragma unroll
    for (int off = 32; off > 0; off >>= 1) r += __shfl_xor(r, off, 64);
    if (lane == 0) op[d] = bf16c(r * 0.0625f);   // /sqrt(64)/(V-1)
  }
}

// ---------------------------------------------------------------------------
// cin_b ch 20..83 = h (j-reordered), 84..95 = 0
// ---------------------------------------------------------------------------
__global__ __launch_bounds__(256)
void pack_cin(const float* __restrict__ h, unsigned short* __restrict__ cin_b) {
  int id = blockIdx.x * 256 + threadIdx.x;
  if (id >= kBV * kHW) return;
  int j = id / kHW, pix = id - j * kHW;
  int src = (j & 1) * 3 + (j >> 1);
  const float* hr = &h[((size_t)src * kHW + pix) * 64];
  unsigned short* o = &cin_b[(size_t)id * 96];
#pragma unroll
  for (int g = 0; g < 16; ++g) {
    float4v vv = *(const float4v*)(hr + g * 4);
    i32x2 pk = {pack2(vv.x, vv.y), pack2(vv.z, vv.w)};
    *(i32x2*)(o + 20 + g * 4) = pk;
  }
  i32x2 z = {0, 0};
  *(i32x2*)(o + 84) = z;
  *(i32x2*)(o + 88) = z;
  *(i32x2*)(o + 92) = z;
}

// ---------------------------------------------------------------------------
// fusedn_b ch 64..127 = BNf(h) (i-order)
// ---------------------------------------------------------------------------
__global__ __launch_bounds__(256)
void pack_fusedn(const float* __restrict__ h, const ConstBuf* __restrict__ cb,
                 unsigned short* __restrict__ fusedn_b) {
  int id = blockIdx.x * 256 + threadIdx.x;
  if (id >= kBV * kHW) return;
  const float* hr = &h[(size_t)id * 64];
  unsigned short* o = &fusedn_b[(size_t)id * 128 + 64];
#pragma unroll
  for (int g = 0; g < 16; ++g) {
    float4v vv = *(const float4v*)(hr + g * 4);
    float r0 = vv.x * cb->bnf_s[64 + g * 4 + 0] + cb->bnf_o[64 + g * 4 + 0];
    float r1 = vv.y * cb->bnf_s[64 + g * 4 + 1] + cb->bnf_o[64 + g * 4 + 1];
    float r2 = vv.z * cb->bnf_s[64 + g * 4 + 2] + cb->bnf_o[64 + g * 4 + 2];
    float r3 = vv.w * cb->bnf_s[64 + g * 4 + 3] + cb->bnf_o[64 + g * 4 + 3];
    i32x2 pk = {pack2(r0, r1), pack2(r2, r3)};
    *(i32x2*)(o + g * 4) = pk;
  }
}

// ---------------------------------------------------------------------------
// Launch
// ---------------------------------------------------------------------------
extern "C" void kernel_launch(void* const* d_in, const int* in_sizes, int n_in,
                              void* d_out, int out_size, void* d_ws, size_t ws_size,
                              hipStream_t stream) {
  (void)in_sizes; (void)n_in; (void)out_size; (void)ws_size;
  const float* x    = (const float*)d_in[0];
  const float* intr = (const float*)d_in[1];
  const float* c2w  = (const float*)d_in[2];
  const float* bn1g = (const float*)d_in[3];
  const float* bn1b = (const float*)d_in[4];
  const float* bn1m = (const float*)d_in[5];
  const float* bn1v = (const float*)d_in[6];
  const float* w1   = (const float*)d_in[7];
  const float* b1   = (const float*)d_in[8];
  const float* bn2g = (const float*)d_in[9];
  const float* bn2b = (const float*)d_in[10];
  const float* bn2m = (const float*)d_in[11];
  const float* bn2v = (const float*)d_in[12];
  const float* w2   = (const float*)d_in[13];
  const float* b2   = (const float*)d_in[14];
  const float* cpw  = (const float*)d_in[15];
  const float* cpb  = (const float*)d_in[16];
  const float* bnfg = (const float*)d_in[17];
  const float* bnfb = (const float*)d_in[18];
  const float* bnfm = (const float*)d_in[19];
  const float* bnfv = (const float*)d_in[20];
  const float* wf   = (const float*)d_in[21];
  const float* bff  = (const float*)d_in[22];

  char* ws = (char*)d_ws;
  ConstBuf* cb            = (ConstBuf*)ws;
  unsigned short* hn_b    = (unsigned short*)(ws + 8192);        // 6*9600*96*2
  unsigned short* h1_b    = (unsigned short*)(ws + 11067392);    // 6*9600*64*2
  float*          h       = (float*)(ws + 18440192);             // 6*9600*64*4
  unsigned short* cin_b   = (unsigned short*)(ws + 33185792);    // 6*9600*96*2
  unsigned short* fused_b = (unsigned short*)(ws + 44244992);    // 6*9600*128*2
  unsigned short* Wp1     = (unsigned short*)(ws + 58990592);    // 995328 B
  unsigned short* Wp2     = (unsigned short*)(ws + 59985920);    // 663552 B
  unsigned short* Wpc     = (unsigned short*)(ws + 60649472);    // 110592 B
  unsigned short* Wpf     = (unsigned short*)(ws + 60760064);    // 1327104 B

  consts_kernel<<<1, 64, 0, stream>>>(intr, c2w, bn1g, bn1b, bn1m, bn1v,
                                      bn2g, bn2b, bn2m, bn2v, bnfg, bnfb, bnfm, bnfv, cb);
  prep_w<9, 96, 67><<<243, 256, 0, stream>>>(w1, Wp1);
  prep_w<9, 64, 64><<<162, 256, 0, stream>>>(w2, Wp2);
  prep_w<3, 96, 84><<<27, 256, 0, stream>>>(cpw, Wpc);
  prep_w<9, 128, 128><<<324, 256, 0, stream>>>(wf, Wpf);
  hn_pack<<<225, 256, 0, stream>>>(x, cb, hn_b);

  dim3 cgrid(8, 10, 6);
  conv_mfma<96, 9, 0><<<cgrid, 512, 0, stream>>>(hn_b, Wp1, b1, cb, nullptr, h1_b);
  conv_mfma<64, 9, 1><<<cgrid, 512, 0, stream>>>(h1_b, Wp2, b2, cb, h, nullptr);
  corr_kernel<<<14400, 256, 0, stream>>>(h, cb, cin_b);
  pack_cin<<<225, 256, 0, stream>>>(h, cin_b);
  conv_mfma<96, 3, 2><<<cgrid, 512, 0, stream>>>(cin_b, Wpc, cpb, cb, nullptr, fused_b);
  pack_fusedn<<<225, 256, 0, stream>>>(h, cb, fused_b);
  conv_mfma<128, 9, 3><<<cgrid, 512, 0, stream>>>(fused_b, Wpf, bff, cb, (float*)d_out, nullptr);
}